// Round 2
// baseline (36123.990 us; speedup 1.0000x reference)
//
#include <hip/hip_runtime.h>
#include <math.h>

#define N_PTS       40000
#define N_ANCH      4000     // ceil(0.1 * 40000)
#define KNN         20
#define FPS_BLOCKS  8
#define FPS_THREADS 1024
#define STRIDE      (FPS_BLOCKS * FPS_THREADS)   // 8192
#define PPT         5                             // 8192*5 = 40960 >= 40000

typedef unsigned long long ull;

// ---------------------------------------------------------------------------
// Workspace layout (first 768 bytes zeroed via hipMemsetAsync each launch):
//   off   0 : double acc                  (loss accumulator)
//   off 256 : ull lines[8][8]             (one 64B line per block:
//                 [0]=A par0 (full f64 bits, relaxed)
//                 [1]=B par0 (packed key, release)   key=[dist46|idxcomp16|tag2]
//                 [2]=A par1  [3]=B par1  [4..7] pad)
//   off 768 : int anchors[4000]
// ---------------------------------------------------------------------------

// ======================= FPS (farthest point sampling) =====================
__global__ __launch_bounds__(FPS_THREADS) void fps_kernel(
    const float* __restrict__ pos, ull* __restrict__ lines,
    int* __restrict__ anchors) {
  const int t    = threadIdx.x;
  const int b    = blockIdx.x;
  const int gtid = b * FPS_THREADS + t;
  const int lane = t & 63;
  const int wave = t >> 6;

  double pdx[PPT], pdy[PPT], pdz[PPT], md[PPT];
  const double a0x = (double)pos[0], a0y = (double)pos[1], a0z = (double)pos[2];

#pragma unroll
  for (int k = 0; k < PPT; ++k) {
    int i = gtid + k * STRIDE;
    if (i < N_PTS) {
      pdx[k] = (double)pos[3 * i];
      pdy[k] = (double)pos[3 * i + 1];
      pdz[k] = (double)pos[3 * i + 2];
      double dx = pdx[k] - a0x, dy = pdy[k] - a0y, dz = pdz[k] - a0z;
      md[k] = dx * dx + dy * dy + dz * dz;
    } else {
      pdx[k] = 0.0; pdy[k] = 0.0; pdz[k] = 0.0;
      md[k] = 0.0;   // pad: dist 0 + huge idx never wins (real winners have md>0)
    }
  }
  if (b == 0 && t == 0) anchors[0] = 0;

  // thread-local argmax (ties -> lowest index, matching np.argmax first-max)
  double bv = -1.0; int bi = 0x7fffffff;
#pragma unroll
  for (int k = 0; k < PPT; ++k) {
    int i  = gtid + k * STRIDE;
    int ii = (i < N_PTS) ? i : 0xFFFF;
    bool bt = (md[k] > bv) || (md[k] == bv && ii < bi);
    bv = bt ? md[k] : bv;
    bi = bt ? ii : bi;
  }

  __shared__ double s_val[16];
  __shared__ int    s_idx[16];

  for (int iter = 1; iter < N_ANCH; ++iter) {
    const int par = iter & 1;
    const ull tag = (ull)(iter & 3);

    // ---- wave argmax reduce (exact f64, min-idx tiebreak) ----
    double rv = bv; int ri = bi;
#pragma unroll
    for (int off = 32; off >= 1; off >>= 1) {
      double ov = __shfl_down(rv, off);
      int    oi = __shfl_down(ri, off);
      bool bt = (ov > rv) || (ov == rv && oi < ri);
      rv = bt ? ov : rv;
      ri = bt ? oi : ri;
    }
    if (lane == 0) { s_val[wave] = rv; s_idx[wave] = ri; }
    __syncthreads();   // the ONLY block barrier per iteration

    // ---- wave0: cross-wave reduce + publish ----
    if (wave == 0) {
      double cv = (lane < 16) ? s_val[lane] : -1.0;
      int    ci = (lane < 16) ? s_idx[lane] : 0x7fffffff;
#pragma unroll
      for (int off = 8; off >= 1; off >>= 1) {
        double ov = __shfl_down(cv, off);
        int    oi = __shfl_down(ci, off);
        bool bt = (ov > cv) || (ov == cv && oi < ci);
        cv = bt ? ov : cv;
        ci = bt ? oi : ci;
      }
      if (lane == 0) {
        ull bits = (ull)__double_as_longlong(cv);   // cv >= 0 -> order-preserving
        ull key  = (bits & ~0x3FFFFull) | ((ull)(0xFFFF - ci) << 2) | tag;
        __hip_atomic_store(&lines[b * 8 + par * 2 + 0], bits,
                           __ATOMIC_RELAXED, __HIP_MEMORY_SCOPE_AGENT);
        __hip_atomic_store(&lines[b * 8 + par * 2 + 1], key,
                           __ATOMIC_RELEASE, __HIP_MEMORY_SCOPE_AGENT);
      }
    }

    // ---- every wave polls all 8 slots independently (no 2nd barrier) ----
    ull myk = 0;
    if (lane < FPS_BLOCKS) {
      ull* slot = &lines[lane * 8 + par * 2 + 1];
      myk = __hip_atomic_load(slot, __ATOMIC_ACQUIRE, __HIP_MEMORY_SCOPE_AGENT);
      while ((myk & 3ull) != tag) {
        __builtin_amdgcn_s_sleep(1);
        myk = __hip_atomic_load(slot, __ATOMIC_ACQUIRE, __HIP_MEMORY_SCOPE_AGENT);
      }
    }
    // butterfly max over the 8 keys (lanes 0..7), then broadcast
    ull m = myk;
#pragma unroll
    for (int off = 1; off < 8; off <<= 1) {
      ull o = __shfl_xor(m, off);
      m = (o > m) ? o : m;
    }
    ull gk = __shfl(m, 0);

    int ix;
    bool samet = (lane < FPS_BLOCKS) && ((myk >> 18) == (gk >> 18));
    ull vote = __ballot(samet);
    if (__popcll(vote) > 1) {
      // truncation tie across blocks (~never): exact f64 arbitration
      double av = -1.0; int ai2 = 0x7fffffff;
      if (samet) {
        ull abits = __hip_atomic_load(&lines[lane * 8 + par * 2 + 0],
                                      __ATOMIC_RELAXED, __HIP_MEMORY_SCOPE_AGENT);
        av  = __longlong_as_double((long long)abits);
        ai2 = 0xFFFF - (int)((myk >> 2) & 0xFFFFull);
      }
#pragma unroll
      for (int off = 1; off < 8; off <<= 1) {
        double ov = __shfl_xor(av, off);
        int    oi = __shfl_xor(ai2, off);
        bool bt = (ov > av) || (ov == av && oi < ai2);
        av  = bt ? ov : av;
        ai2 = bt ? oi : ai2;
      }
      ix = __shfl(ai2, 0);
    } else {
      ix = 0xFFFF - (int)((gk >> 2) & 0xFFFFull);
    }
    if (b == 0 && t == 0) anchors[iter] = ix;

    // ---- fetch winner position (broadcast load) ----
    double wx = (double)pos[3 * ix];
    double wy = (double)pos[3 * ix + 1];
    double wz = (double)pos[3 * ix + 2];

    // ---- fused min-update + next thread-local argmax ----
    bv = -1.0; bi = 0x7fffffff;
#pragma unroll
    for (int k = 0; k < PPT; ++k) {
      double dx = pdx[k] - wx, dy = pdy[k] - wy, dz = pdz[k] - wz;
      double d  = dx * dx + dy * dy + dz * dz;
      md[k] = fmin(md[k], d);
      int i  = gtid + k * STRIDE;
      int ii = (i < N_PTS) ? i : 0xFFFF;
      bool bt = (md[k] > bv) || (md[k] == bv && ii < bi);
      bv = bt ? md[k] : bv;
      bi = bt ? ii : bi;
    }
  }
}

// ============== symmetric 3x3: eigenvector of largest eigenvalue ===========
__device__ static inline void eig3_maxvec(double xx, double xy, double xz,
                                          double yy, double yz, double zz,
                                          double& v0, double& v1, double& v2) {
  double q  = (xx + yy + zz) / 3.0;
  double p1 = xy * xy + xz * xz + yz * yz;
  double a00 = xx - q, a11 = yy - q, a22 = zz - q;
  double p2 = a00 * a00 + a11 * a11 + a22 * a22 + 2.0 * p1;
  if (p2 < 1e-300) { v0 = 1.0; v1 = 0.0; v2 = 0.0; return; }
  double p   = sqrt(p2 / 6.0);
  double inv = 1.0 / p;
  double b00 = a00 * inv, b01 = xy * inv, b02 = xz * inv;
  double b11 = a11 * inv, b12 = yz * inv, b22 = a22 * inv;
  double detB = b00 * (b11 * b22 - b12 * b12)
              - b01 * (b01 * b22 - b12 * b02)
              + b02 * (b01 * b12 - b11 * b02);
  double r = fmin(1.0, fmax(-1.0, detB * 0.5));
  double phi = acos(r) / 3.0;
  double lam = q + 2.0 * p * cos(phi);   // largest eigenvalue

  double r0x = xx - lam, r0y = xy,       r0z = xz;
  double r1x = xy,       r1y = yy - lam, r1z = yz;
  double r2x = xz,       r2y = yz,       r2z = zz - lam;
  double c0x = r0y * r1z - r0z * r1y, c0y = r0z * r1x - r0x * r1z, c0z = r0x * r1y - r0y * r1x;
  double c1x = r0y * r2z - r0z * r2y, c1y = r0z * r2x - r0x * r2z, c1z = r0x * r2y - r0y * r2x;
  double c2x = r1y * r2z - r1z * r2y, c2y = r1z * r2x - r1x * r2z, c2z = r1x * r2y - r1y * r2x;
  double n0 = c0x * c0x + c0y * c0y + c0z * c0z;
  double n1 = c1x * c1x + c1y * c1y + c1z * c1z;
  double n2 = c2x * c2x + c2y * c2y + c2z * c2z;
  double bx = c0x, by = c0y, bz = c0z, bn = n0;
  if (n1 > bn) { bx = c1x; by = c1y; bz = c1z; bn = n1; }
  if (n2 > bn) { bx = c2x; by = c2y; bz = c2z; bn = n2; }
  if (bn < 1e-280) { v0 = 1.0; v1 = 0.0; v2 = 0.0; return; }
  double s = 1.0 / sqrt(bn);
  v0 = bx * s; v1 = by * s; v2 = bz * s;
}

// ================= KNN + principal direction + loss term ===================
__global__ __launch_bounds__(64) void knn_kernel(
    const float* __restrict__ pos, const float* __restrict__ vec_pred,
    const int* __restrict__ anchors, double* __restrict__ acc) {
  const int aidx = blockIdx.x;     // anchor ordinal i
  const int lane = threadIdx.x;
  const int ai   = anchors[aidx];
  const float ax = pos[3 * ai], ay = pos[3 * ai + 1], az = pos[3 * ai + 2];

  unsigned long long key[KNN];
#pragma unroll
  for (int s = 0; s < KNN; ++s) key[s] = ~0ull;
  unsigned long long kmax = ~0ull; int smax = 0;

  for (int k = 0; k < N_PTS / 64; ++k) {     // 625 candidates per lane
    int j = (k << 6) + lane;
    float dx = pos[3 * j] - ax, dy = pos[3 * j + 1] - ay, dz = pos[3 * j + 2] - az;
    float d  = dx * dx + dy * dy + dz * dz;
    unsigned long long nk = ((unsigned long long)__float_as_uint(d) << 32) | (unsigned int)j;
    if (nk < kmax) {
#pragma unroll
      for (int s = 0; s < KNN; ++s) key[s] = (s == smax) ? nk : key[s];
      kmax = 0ull; smax = 0;
#pragma unroll
      for (int s = 0; s < KNN; ++s) {
        bool g = key[s] > kmax;
        kmax = g ? key[s] : kmax;
        smax = g ? s : smax;
      }
    }
  }

  __shared__ unsigned long long lk[64 * KNN];
#pragma unroll
  for (int s = 0; s < KNN; ++s) lk[lane * KNN + s] = key[s];
  __syncthreads();
  __shared__ int w[KNN];
  for (int r = 0; r < KNN; ++r) {
    unsigned long long lmin = ~0ull; int ls = 0;
#pragma unroll
    for (int s = 0; s < KNN; ++s) {
      unsigned long long kk = lk[lane * KNN + s];
      bool l = kk < lmin;
      lmin = l ? kk : lmin;
      ls   = l ? s : ls;
    }
    unsigned long long mv = lmin; int ml = lane; int ms = ls;
#pragma unroll
    for (int off = 32; off >= 1; off >>= 1) {
      unsigned long long ov = __shfl_down(mv, off);
      int ol = __shfl_down(ml, off);
      int os = __shfl_down(ms, off);
      if (ov < mv) { mv = ov; ml = ol; ms = os; }
    }
    mv = __shfl(mv, 0); ml = __shfl(ml, 0); ms = __shfl(ms, 0);
    if (lane == ml) lk[ml * KNN + ms] = ~0ull;    // consume winner
    if (lane == 0)  w[r] = (int)(mv & 0xffffffffull);
    __syncthreads();
  }

  if (lane == 0) {
    double mx = 0, my = 0, mz = 0;
    for (int r = 0; r < KNN; ++r) {
      int p = w[r];
      mx += (double)pos[3 * p]; my += (double)pos[3 * p + 1]; mz += (double)pos[3 * p + 2];
    }
    mx /= KNN; my /= KNN; mz /= KNN;
    double xx = 0, xy = 0, xz = 0, yy = 0, yz = 0, zz = 0;
    for (int r = 0; r < KNN; ++r) {
      int p = w[r];
      double cx = (double)pos[3 * p]     - mx;
      double cy = (double)pos[3 * p + 1] - my;
      double cz = (double)pos[3 * p + 2] - mz;
      xx += cx * cx; xy += cx * cy; xz += cx * cz;
      yy += cy * cy; yz += cy * cz; zz += cz * cz;
    }
    double v0, v1, v2;
    eig3_maxvec(xx, xy, xz, yy, yz, zz, v0, v1, v2);

    double a0 = vec_pred[3 * aidx], a1 = vec_pred[3 * aidx + 1], a2 = vec_pred[3 * aidx + 2];
    double an = sqrt(a0 * a0 + a1 * a1 + a2 * a2);
    double bn = sqrt(v0 * v0 + v1 * v1 + v2 * v2);
    double denom = fmax(an, 1e-8) * fmax(bn, 1e-8);
    double c = fabs((a0 * v0 + a1 * v1 + a2 * v2) / denom);
    atomicAdd(acc, log(c + 1e-6));
  }
}

__global__ void finalize_kernel(const double* __restrict__ acc, float* __restrict__ out) {
  out[0] = (float)(-acc[0] / (double)N_ANCH);
}

// ===========================================================================
extern "C" void kernel_launch(void* const* d_in, const int* in_sizes, int n_in,
                              void* d_out, int out_size, void* d_ws, size_t ws_size,
                              hipStream_t stream) {
  (void)in_sizes; (void)n_in; (void)out_size; (void)ws_size;
  const float* vec_pred = (const float*)d_in[0];
  const float* pos      = (const float*)d_in[1];
  float* out = (float*)d_out;

  char* ws = (char*)d_ws;
  double* acc     = (double*)(ws + 0);
  ull*    lines   = (ull*)(ws + 256);
  int*    anchors = (int*)(ws + 768);

  hipMemsetAsync(d_ws, 0, 768, stream);   // zero acc + publish lines
  hipLaunchKernelGGL(fps_kernel, dim3(FPS_BLOCKS), dim3(FPS_THREADS), 0, stream,
                     pos, lines, anchors);
  hipLaunchKernelGGL(knn_kernel, dim3(N_ANCH), dim3(64), 0, stream,
                     pos, vec_pred, anchors, acc);
  hipLaunchKernelGGL(finalize_kernel, dim3(1), dim3(1), 0, stream, acc, out);
}

// Round 3
// 10503.171 us; speedup vs baseline: 3.4393x; 3.4393x over previous
//
#include <hip/hip_runtime.h>
#include <math.h>

#define N_PTS       40000
#define N_ANCH      4000     // ceil(0.1 * 40000)
#define KNN         20
#define NB          8        // fps blocks
#define BT          256      // threads per block (all blocks)
#define STRIDE      (NB * BT)          // 2048
#define PPT         20                 // 2048*20 = 40960 >= 40000
#define TOPT        8                  // published candidates per block
#define SCAP        60                 // max anchors per batch (pool=64)

typedef unsigned long long ull;

#define LD_ACQ(p)    __hip_atomic_load((p),  __ATOMIC_ACQUIRE, __HIP_MEMORY_SCOPE_AGENT)
#define LD_RLX(p)    __hip_atomic_load((p),  __ATOMIC_RELAXED, __HIP_MEMORY_SCOPE_AGENT)
#define ST_REL(p,v)  __hip_atomic_store((p), (v), __ATOMIC_RELEASE, __HIP_MEMORY_SCOPE_AGENT)
#define ST_RLX(p,v)  __hip_atomic_store((p), (v), __ATOMIC_RELAXED, __HIP_MEMORY_SCOPE_AGENT)

// Workspace layout:
//   off    0 : double acc            (zeroed)
//   off   64 : int flag[8]           (zeroed; monotone batch counters)
//   off  256 : ull ent[8][2][8][2]   (per block, per parity, 8 slots of {valbits, idx})
//   off 4096 : int anchors[4000]     (memset 0xFF -> -1)

__device__ __forceinline__ double dist64(double px, double py, double pz,
                                         double wx, double wy, double wz) {
  double dx = px - wx, dy = py - wy, dz = pz - wz;
  return dx * dx + dy * dy + dz * dz;
}

struct FpsSm {
  double sval[4]; int sidx[4];
  double pubV[TOPT]; int pubI[TOPT];
  float bwx[SCAP], bwy[SCAP], bwz[SCAP];
  int S;
};
struct KnnSm { ull m4[4]; ull g; int w[KNN]; int ai; };
union Smem { FpsSm f; KnnSm k; };

// ============== symmetric 3x3: eigenvector of largest eigenvalue ===========
__device__ static inline void eig3_maxvec(double xx, double xy, double xz,
                                          double yy, double yz, double zz,
                                          double& v0, double& v1, double& v2) {
  double q  = (xx + yy + zz) / 3.0;
  double p1 = xy * xy + xz * xz + yz * yz;
  double a00 = xx - q, a11 = yy - q, a22 = zz - q;
  double p2 = a00 * a00 + a11 * a11 + a22 * a22 + 2.0 * p1;
  if (p2 < 1e-300) { v0 = 1.0; v1 = 0.0; v2 = 0.0; return; }
  double p   = sqrt(p2 / 6.0);
  double inv = 1.0 / p;
  double b00 = a00 * inv, b01 = xy * inv, b02 = xz * inv;
  double b11 = a11 * inv, b12 = yz * inv, b22 = a22 * inv;
  double detB = b00 * (b11 * b22 - b12 * b12)
              - b01 * (b01 * b22 - b12 * b02)
              + b02 * (b01 * b12 - b11 * b02);
  double r = fmin(1.0, fmax(-1.0, detB * 0.5));
  double phi = acos(r) / 3.0;
  double lam = q + 2.0 * p * cos(phi);   // largest eigenvalue

  double r0x = xx - lam, r0y = xy,       r0z = xz;
  double r1x = xy,       r1y = yy - lam, r1z = yz;
  double r2x = xz,       r2y = yz,       r2z = zz - lam;
  double c0x = r0y * r1z - r0z * r1y, c0y = r0z * r1x - r0x * r1z, c0z = r0x * r1y - r0y * r1x;
  double c1x = r0y * r2z - r0z * r2y, c1y = r0z * r2x - r0x * r2z, c1z = r0x * r2y - r0y * r2x;
  double c2x = r1y * r2z - r1z * r2y, c2y = r1z * r2x - r1x * r2z, c2z = r1x * r2y - r1y * r2x;
  double n0 = c0x * c0x + c0y * c0y + c0z * c0z;
  double n1 = c1x * c1x + c1y * c1y + c1z * c1z;
  double n2 = c2x * c2x + c2y * c2y + c2z * c2z;
  double bx = c0x, by = c0y, bz = c0z, bn = n0;
  if (n1 > bn) { bx = c1x; by = c1y; bz = c1z; bn = n1; }
  if (n2 > bn) { bx = c2x; by = c2y; bz = c2z; bn = n2; }
  if (bn < 1e-280) { v0 = 1.0; v1 = 0.0; v2 = 0.0; return; }
  double s = 1.0 / sqrt(bn);
  v0 = bx * s; v1 = by * s; v2 = bz * s;
}

// ===========================================================================
__global__ __launch_bounds__(BT, 2) void fps_knn_kernel(
    const float* __restrict__ pos, const float* __restrict__ vec_pred,
    int* __restrict__ flag, ull* __restrict__ ent,
    int* __restrict__ anchors, double* __restrict__ acc) {
  __shared__ Smem sm;
  const int t    = threadIdx.x;
  const int lane = t & 63;
  const int wave = t >> 6;

  if (blockIdx.x < NB) {
    // =========================== FPS (batched) ============================
    const int b    = blockIdx.x;
    const int gtid = b * BT + t;

    double pdx[PPT], pdy[PPT], pdz[PPT], md[PPT];
    const double a0x = (double)pos[0], a0y = (double)pos[1], a0z = (double)pos[2];
#pragma unroll
    for (int k = 0; k < PPT; ++k) {
      int i = gtid + k * STRIDE;
      if (i < N_PTS) {
        pdx[k] = (double)pos[3 * i];
        pdy[k] = (double)pos[3 * i + 1];
        pdz[k] = (double)pos[3 * i + 2];
        md[k]  = dist64(pdx[k], pdy[k], pdz[k], a0x, a0y, a0z);
      } else {
        pdx[k] = 0.0; pdy[k] = 0.0; pdz[k] = 0.0;
        md[k]  = -1.0e300;   // pad: never wins
      }
    }
    if (b == 0 && t == 0) ST_REL(anchors + 0, 0);

    // maintained thread-local argmax (ties -> lowest global index)
    double bv = -1.0e301; int bi = 0x7fffffff;
#pragma unroll
    for (int k = 0; k < PPT; ++k) {
      int i = gtid + k * STRIDE;
      bool bt = (md[k] > bv) || (md[k] == bv && i < bi);
      bv = bt ? md[k] : bv; bi = bt ? i : bi;
    }

    int nsel  = 1;
    int batch = 0;
#pragma unroll 1
    while (nsel < N_ANCH) {
      batch++;
      const int par = batch & 1;
      unsigned mask = 0;

      // ---- extract block top-8 by (md desc, idx asc) ----
#pragma unroll 1
      for (int r = 0; r < TOPT; ++r) {
        double rv = bv; int ri = bi;
#pragma unroll
        for (int off = 32; off >= 1; off >>= 1) {
          double ov = __shfl_down(rv, off);
          int    oi = __shfl_down(ri, off);
          bool bt = (ov > rv) || (ov == rv && oi < ri);
          rv = bt ? ov : rv; ri = bt ? oi : ri;
        }
        if (lane == 0) { sm.f.sval[wave] = rv; sm.f.sidx[wave] = ri; }
        __syncthreads();
        if (t == 0) {
          double cv = sm.f.sval[0]; int ci = sm.f.sidx[0];
#pragma unroll
          for (int w = 1; w < 4; ++w) {
            double ov = sm.f.sval[w]; int oi = sm.f.sidx[w];
            bool bt = (ov > cv) || (ov == cv && oi < ci);
            cv = bt ? ov : cv; ci = bt ? oi : ci;
          }
          sm.f.pubV[r] = cv; sm.f.pubI[r] = ci;
        }
        __syncthreads();
        int wi = sm.f.pubI[r];
        if ((wi & (STRIDE - 1)) == gtid) {       // owner: mask & rescan
          mask |= (1u << (wi / STRIDE));
          bv = -1.0e301; bi = 0x7fffffff;
#pragma unroll
          for (int k = 0; k < PPT; ++k) {
            if (!((mask >> k) & 1u)) {
              int i = gtid + k * STRIDE;
              bool bt = (md[k] > bv) || (md[k] == bv && i < bi);
              bv = bt ? md[k] : bv; bi = bt ? i : bi;
            }
          }
        }
      }

      // ---- publish / poll / pool-select (wave0 only) ----
      if (wave == 0) {
        if (lane < TOPT) {
          double v = sm.f.pubV[lane]; int ix = sm.f.pubI[lane];
          ull* e = ent + (ull)(b * 32 + par * 16 + lane * 2);
          ST_RLX(e,     (ull)__double_as_longlong(v));
          ST_RLX(e + 1, (ull)(unsigned)ix);
        }
        __threadfence();
        if (lane == 0) ST_REL(flag + b, batch);
        if (lane < NB) {
          while (LD_ACQ(flag + lane) < batch) __builtin_amdgcn_s_sleep(2);
        }
        __threadfence();

        ull* e2 = ent + (ull)((lane >> 3) * 32 + par * 16 + (lane & 7) * 2);
        double cval = __longlong_as_double((long long)LD_RLX(e2));
        int    cidx = (int)LD_RLX(e2 + 1);
        float cfx = pos[3 * cidx], cfy = pos[3 * cidx + 1], cfz = pos[3 * cidx + 2];
        double cx = (double)cfx, cy = (double)cfy, cz = (double)cfz;

        // B_max = max over blocks of their 8th (smallest published) value
        double bsrc = ((lane & 7) == 7) ? cval : -1.0e301;
#pragma unroll
        for (int off = 1; off < 64; off <<= 1) {
          double o = __shfl_xor(bsrc, off);
          bsrc = (o > bsrc) ? o : bsrc;
        }
        const double Bmax = bsrc;

        int cap = N_ANCH - nsel; if (cap > SCAP) cap = SCAP;
        int S = 0;
#pragma unroll 1
        while (S < cap) {
          double wv = cval; int wix = cidx;
#pragma unroll
          for (int off = 1; off < 64; off <<= 1) {
            double ov = __shfl_xor(wv, off);
            int    oi = __shfl_xor(wix, off);
            bool bt = (ov > wv) || (ov == wv && oi < wix);
            wv = bt ? ov : wv; wix = bt ? oi : wix;
          }
          if (S != 0 && !(wv > Bmax)) break;   // unpublished point could beat it
          ull bal = __ballot(cidx == wix);
          int wlane = __ffsll(bal) - 1;
          float fx = __shfl(cfx, wlane), fy = __shfl(cfy, wlane), fz = __shfl(cfz, wlane);
          if (lane == 0) {
            sm.f.bwx[S] = fx; sm.f.bwy[S] = fy; sm.f.bwz[S] = fz;
            if (b == 0) ST_REL(anchors + nsel + S, wix);
          }
          double d = dist64(cx, cy, cz, (double)fx, (double)fy, (double)fz);
          cval = fmin(cval, d);
          if (cidx == wix) cval = -1.0e301;    // consume winner
          S++;
        }
        if (lane == 0) sm.f.S = S;
      }
      __syncthreads();

      // ---- apply the batch's winners to md (exact f64 chain, in order) ----
      const int S = sm.f.S;
#pragma unroll 1
      for (int s = 0; s < S; ++s) {
        double wx = (double)sm.f.bwx[s];
        double wy = (double)sm.f.bwy[s];
        double wz = (double)sm.f.bwz[s];
#pragma unroll
        for (int k = 0; k < PPT; ++k)
          md[k] = fmin(md[k], dist64(pdx[k], pdy[k], pdz[k], wx, wy, wz));
      }
      nsel += S;

      // refresh thread-local argmax
      bv = -1.0e301; bi = 0x7fffffff;
#pragma unroll
      for (int k = 0; k < PPT; ++k) {
        int i = gtid + k * STRIDE;
        bool bt = (md[k] > bv) || (md[k] == bv && i < bi);
        bv = bt ? md[k] : bv; bi = bt ? i : bi;
      }
      __syncthreads();   // protect sm.f.bw* before next batch overwrites LDS
    }
  } else {
    // ========================= KNN (anchor-polling) =======================
    const int aidx = blockIdx.x - NB;
    if (t == 0) {
      int a;
      while ((a = LD_ACQ(anchors + aidx)) < 0) __builtin_amdgcn_s_sleep(16);
      sm.k.ai = a;
    }
    __syncthreads();
    const int ai = sm.k.ai;
    const float ax = pos[3 * ai], ay = pos[3 * ai + 1], az = pos[3 * ai + 2];

    // per-thread top-20 smallest u64 keys (f32 dist bits | idx)
    ull key[KNN];
#pragma unroll
    for (int s = 0; s < KNN; ++s) key[s] = ~0ull;
    ull kmax = ~0ull; int smax = 0;
#pragma unroll 1
    for (int k = 0; k < (N_PTS + BT - 1) / BT; ++k) {
      int j = k * BT + t;
      if (j < N_PTS) {
        float dx = pos[3 * j] - ax, dy = pos[3 * j + 1] - ay, dz = pos[3 * j + 2] - az;
        float d  = dx * dx + dy * dy + dz * dz;
        ull nk = ((ull)__float_as_uint(d) << 32) | (unsigned)j;
        if (nk < kmax) {
#pragma unroll
          for (int s = 0; s < KNN; ++s) key[s] = (s == smax) ? nk : key[s];
          kmax = 0ull; smax = 0;
#pragma unroll
          for (int s = 0; s < KNN; ++s) {
            bool g = key[s] > kmax;
            kmax = g ? key[s] : kmax;
            smax = g ? s : smax;
          }
        }
      }
    }

    // block-wide merge: 20 extract-min rounds over per-thread lists
    ull lmin = ~0ull; int ls = 0;
#pragma unroll
    for (int s = 0; s < KNN; ++s) {
      if (key[s] < lmin) { lmin = key[s]; ls = s; }
    }
#pragma unroll 1
    for (int r = 0; r < KNN; ++r) {
      ull mv = lmin;
#pragma unroll
      for (int off = 32; off >= 1; off >>= 1) {
        ull ov = __shfl_down(mv, off);
        mv = (ov < mv) ? ov : mv;
      }
      if (lane == 0) sm.k.m4[wave] = mv;
      __syncthreads();
      if (t == 0) {
        ull g = sm.k.m4[0];
#pragma unroll
        for (int w = 1; w < 4; ++w) g = (sm.k.m4[w] < g) ? sm.k.m4[w] : g;
        sm.k.g = g;
        sm.k.w[r] = (int)(g & 0xffffffffull);
      }
      __syncthreads();
      ull g = sm.k.g;
      if (lmin == g) {          // unique owner consumes & rescans
        key[ls] = ~0ull;
        lmin = ~0ull; ls = 0;
#pragma unroll
        for (int s = 0; s < KNN; ++s) {
          if (key[s] < lmin) { lmin = key[s]; ls = s; }
        }
      }
    }

    if (t == 0) {
      double mx = 0, my = 0, mz = 0;
      for (int r = 0; r < KNN; ++r) {
        int p = sm.k.w[r];
        mx += (double)pos[3 * p]; my += (double)pos[3 * p + 1]; mz += (double)pos[3 * p + 2];
      }
      mx /= KNN; my /= KNN; mz /= KNN;
      double xx = 0, xy = 0, xz = 0, yy = 0, yz = 0, zz = 0;
      for (int r = 0; r < KNN; ++r) {
        int p = sm.k.w[r];
        double cx = (double)pos[3 * p]     - mx;
        double cy = (double)pos[3 * p + 1] - my;
        double cz = (double)pos[3 * p + 2] - mz;
        xx += cx * cx; xy += cx * cy; xz += cx * cz;
        yy += cy * cy; yz += cy * cz; zz += cz * cz;
      }
      double v0, v1, v2;
      eig3_maxvec(xx, xy, xz, yy, yz, zz, v0, v1, v2);

      double a0 = vec_pred[3 * aidx], a1 = vec_pred[3 * aidx + 1], a2 = vec_pred[3 * aidx + 2];
      double an = sqrt(a0 * a0 + a1 * a1 + a2 * a2);
      double bn = sqrt(v0 * v0 + v1 * v1 + v2 * v2);
      double denom = fmax(an, 1e-8) * fmax(bn, 1e-8);
      double c = fabs((a0 * v0 + a1 * v1 + a2 * v2) / denom);
      atomicAdd(acc, log(c + 1e-6));
    }
  }
}

__global__ void finalize_kernel(const double* __restrict__ acc, float* __restrict__ out) {
  out[0] = (float)(-acc[0] / (double)N_ANCH);
}

// ===========================================================================
extern "C" void kernel_launch(void* const* d_in, const int* in_sizes, int n_in,
                              void* d_out, int out_size, void* d_ws, size_t ws_size,
                              hipStream_t stream) {
  (void)in_sizes; (void)n_in; (void)out_size; (void)ws_size;
  const float* vec_pred = (const float*)d_in[0];
  const float* pos      = (const float*)d_in[1];
  float* out = (float*)d_out;

  char* ws = (char*)d_ws;
  double* acc     = (double*)(ws + 0);
  int*    flag    = (int*)(ws + 64);
  ull*    ent     = (ull*)(ws + 256);
  int*    anchors = (int*)(ws + 4096);

  hipMemsetAsync(ws, 0, 256, stream);                   // acc + flags
  hipMemsetAsync(ws + 4096, 0xFF, N_ANCH * 4, stream);  // anchors = -1
  hipLaunchKernelGGL(fps_knn_kernel, dim3(NB + N_ANCH), dim3(BT), 0, stream,
                     pos, vec_pred, flag, ent, anchors, acc);
  hipLaunchKernelGGL(finalize_kernel, dim3(1), dim3(1), 0, stream, acc, out);
}

// Round 4
// 10298.644 us; speedup vs baseline: 3.5076x; 1.0199x over previous
//
#include <hip/hip_runtime.h>
#include <math.h>

#define N_PTS       40000
#define N_ANCH      4000     // ceil(0.1 * 40000)
#define KNN         20
#define NB          16       // fps blocks
#define BT          256      // threads per block (all blocks)
#define STRIDE      (NB * BT)          // 4096
#define PPT         10                 // 4096*10 = 40960 >= 40000
#define TOPT        8                  // published candidates per block
#define POOL        (NB * TOPT)        // 128
#define SCAP        64                 // max anchors per batch

typedef unsigned long long ull;

#define LD_ACQ(p)    __hip_atomic_load((p),  __ATOMIC_ACQUIRE, __HIP_MEMORY_SCOPE_AGENT)
#define LD_RLX(p)    __hip_atomic_load((p),  __ATOMIC_RELAXED, __HIP_MEMORY_SCOPE_AGENT)
#define ST_REL(p,v)  __hip_atomic_store((p), (v), __ATOMIC_RELEASE, __HIP_MEMORY_SCOPE_AGENT)
#define ST_RLX(p,v)  __hip_atomic_store((p), (v), __ATOMIC_RELAXED, __HIP_MEMORY_SCOPE_AGENT)

// Workspace layout:
//   off    0 : double acc              (zeroed)
//   off  256 : ull keys[2][128]        (zeroed; tagged words: idx<<2 | batch&3)
//   off 4096 : ull exact[2][128]       (f64 dist bits; fenced before key store)
//   off 8192 : int anchors[4000]       (memset 0xFF -> -1)

__device__ __forceinline__ double dist64(double px, double py, double pz,
                                         double wx, double wy, double wz) {
  double dx = px - wx, dy = py - wy, dz = pz - wz;
  return dx * dx + dy * dy + dz * dz;
}

struct FpsSm {
  double wtV[4][TOPT]; int wtI[4][TOPT];   // per-wave top-8
  double bw[SCAP][3];                      // batch winners (f64 coords)
  int S;
};
struct KnnSm { ull m4[4]; ull g; int w[KNN]; int ai; };
union Smem { FpsSm f; KnnSm k; };

// ============== symmetric 3x3: eigenvector of largest eigenvalue ===========
__device__ static inline void eig3_maxvec(double xx, double xy, double xz,
                                          double yy, double yz, double zz,
                                          double& v0, double& v1, double& v2) {
  double q  = (xx + yy + zz) / 3.0;
  double p1 = xy * xy + xz * xz + yz * yz;
  double a00 = xx - q, a11 = yy - q, a22 = zz - q;
  double p2 = a00 * a00 + a11 * a11 + a22 * a22 + 2.0 * p1;
  if (p2 < 1e-300) { v0 = 1.0; v1 = 0.0; v2 = 0.0; return; }
  double p   = sqrt(p2 / 6.0);
  double inv = 1.0 / p;
  double b00 = a00 * inv, b01 = xy * inv, b02 = xz * inv;
  double b11 = a11 * inv, b12 = yz * inv, b22 = a22 * inv;
  double detB = b00 * (b11 * b22 - b12 * b12)
              - b01 * (b01 * b22 - b12 * b02)
              + b02 * (b01 * b12 - b11 * b02);
  double r = fmin(1.0, fmax(-1.0, detB * 0.5));
  double phi = acos(r) / 3.0;
  double lam = q + 2.0 * p * cos(phi);   // largest eigenvalue

  double r0x = xx - lam, r0y = xy,       r0z = xz;
  double r1x = xy,       r1y = yy - lam, r1z = yz;
  double r2x = xz,       r2y = yz,       r2z = zz - lam;
  double c0x = r0y * r1z - r0z * r1y, c0y = r0z * r1x - r0x * r1z, c0z = r0x * r1y - r0y * r1x;
  double c1x = r0y * r2z - r0z * r2y, c1y = r0z * r2x - r0x * r2z, c1z = r0x * r2y - r0y * r2x;
  double c2x = r1y * r2z - r1z * r2y, c2y = r1z * r2x - r1x * r2z, c2z = r1x * r2y - r1y * r2x;
  double n0 = c0x * c0x + c0y * c0y + c0z * c0z;
  double n1 = c1x * c1x + c1y * c1y + c1z * c1z;
  double n2 = c2x * c2x + c2y * c2y + c2z * c2z;
  double bx = c0x, by = c0y, bz = c0z, bn = n0;
  if (n1 > bn) { bx = c1x; by = c1y; bz = c1z; bn = n1; }
  if (n2 > bn) { bx = c2x; by = c2y; bz = c2z; bn = n2; }
  if (bn < 1e-280) { v0 = 1.0; v1 = 0.0; v2 = 0.0; return; }
  double s = 1.0 / sqrt(bn);
  v0 = bx * s; v1 = by * s; v2 = bz * s;
}

// ===========================================================================
__global__ __launch_bounds__(BT, 2) void fps_knn_kernel(
    const float* __restrict__ pos, const float* __restrict__ vec_pred,
    ull* __restrict__ keys, ull* __restrict__ exact,
    int* __restrict__ anchors, double* __restrict__ acc) {
  __shared__ Smem sm;
  const int t    = threadIdx.x;
  const int lane = t & 63;
  const int wave = t >> 6;

  if (blockIdx.x < NB) {
    // =========================== FPS (batched) ============================
    const int b    = blockIdx.x;
    const int gtid = b * BT + t;

    float px[PPT], py[PPT], pz[PPT];   // f32 coords (exact; cvt to f64 is lossless)
    double md[PPT];
    const double a0x = (double)pos[0], a0y = (double)pos[1], a0z = (double)pos[2];
#pragma unroll
    for (int k = 0; k < PPT; ++k) {
      int i = gtid + k * STRIDE;
      if (i < N_PTS) {
        px[k] = pos[3 * i]; py[k] = pos[3 * i + 1]; pz[k] = pos[3 * i + 2];
        md[k] = dist64((double)px[k], (double)py[k], (double)pz[k], a0x, a0y, a0z);
      } else {
        px[k] = 0.f; py[k] = 0.f; pz[k] = 0.f;
        md[k] = -1.0e300;   // pad: never wins (only k=9 for gtid>=3136)
      }
    }
    if (b == 0 && t == 0) ST_REL(anchors + 0, 0);

    // maintained thread-local argmax (ties -> lowest global index)
    double bv = -1.0e301; int bi = 0x7fffffff;
#pragma unroll
    for (int k = 0; k < PPT; ++k) {
      int i = gtid + k * STRIDE;
      bool bt = (md[k] > bv) || (md[k] == bv && i < bi);
      bv = bt ? md[k] : bv; bi = bt ? i : bi;
    }

    int nsel  = 1;
    int batch = 0;
#pragma unroll 1
    while (nsel < N_ANCH) {
      batch++;
      const int par = batch & 1;
      const ull tag = (ull)(batch & 3);

      // ---- per-wave top-8 (shuffle-only butterflies, no barriers) ----
      unsigned mask = 0;
#pragma unroll 1
      for (int r = 0; r < TOPT; ++r) {
        double rv = bv; int ri = bi;
#pragma unroll
        for (int off = 1; off < 64; off <<= 1) {
          double ov = __shfl_xor(rv, off);
          int    oi = __shfl_xor(ri, off);
          bool bt = (ov > rv) || (ov == rv && oi < ri);
          rv = bt ? ov : rv; ri = bt ? oi : ri;
        }
        if (ri == bi && bi != 0x7fffffff) {   // unique owner: mask & rescan
          mask |= 1u << ((ri - gtid) >> 12);  // STRIDE = 4096 = 2^12
          bv = -1.0e301; bi = 0x7fffffff;
#pragma unroll
          for (int k = 0; k < PPT; ++k) {
            if (!((mask >> k) & 1u)) {
              int i = gtid + k * STRIDE;
              bool bt = (md[k] > bv) || (md[k] == bv && i < bi);
              bv = bt ? md[k] : bv; bi = bt ? i : bi;
            }
          }
        }
        if (lane == r) { sm.f.wtV[wave][r] = rv; sm.f.wtI[wave][r] = ri; }
      }
      __syncthreads();

      // ---- wave0: merge 32 -> top-8, publish, poll, pool-select ----
      if (wave == 0) {
        double mv = (lane < 32) ? sm.f.wtV[lane >> 3][lane & 7] : -1.0e301;
        int    mi = (lane < 32) ? sm.f.wtI[lane >> 3][lane & 7] : 0x7fffffff;
        double pv = -1.0e301; int pix = 0;
#pragma unroll 1
        for (int r = 0; r < TOPT; ++r) {
          double rv = mv; int ri = mi;
#pragma unroll
          for (int off = 1; off < 64; off <<= 1) {
            double ov = __shfl_xor(rv, off);
            int    oi = __shfl_xor(ri, off);
            bool bt = (ov > rv) || (ov == rv && oi < ri);
            rv = bt ? ov : rv; ri = bt ? oi : ri;
          }
          if (mi == ri) mv = -1.0e301;         // consume (owner unique)
          if (lane == r) { pv = rv; pix = ri; }
        }
        // publish: exact f64 first, fence, then tagged key
        if (lane < TOPT)
          ST_RLX(exact + par * POOL + b * TOPT + lane, (ull)__double_as_longlong(pv));
        __threadfence();
        if (lane < TOPT)
          ST_RLX(keys + par * POOL + b * TOPT + lane, ((ull)(unsigned)pix << 2) | tag);

        // poll 2 slots per lane until tag matches
        ull* kb = keys + par * POOL;
        ull k0 = LD_RLX(kb + lane);
        while ((k0 & 3ull) != tag) { __builtin_amdgcn_s_sleep(1); k0 = LD_RLX(kb + lane); }
        ull k1 = LD_RLX(kb + lane + 64);
        while ((k1 & 3ull) != tag) { __builtin_amdgcn_s_sleep(1); k1 = LD_RLX(kb + lane + 64); }
        __threadfence();
        double cv0 = __longlong_as_double((long long)LD_RLX(exact + par * POOL + lane));
        double cv1 = __longlong_as_double((long long)LD_RLX(exact + par * POOL + lane + 64));
        int ci0 = (int)(k0 >> 2), ci1 = (int)(k1 >> 2);
        float cfx0 = pos[3 * ci0], cfy0 = pos[3 * ci0 + 1], cfz0 = pos[3 * ci0 + 2];
        float cfx1 = pos[3 * ci1], cfy1 = pos[3 * ci1 + 1], cfz1 = pos[3 * ci1 + 2];

        // Bmax = max over 16 blocks of their 8th (smallest published) value
        double bsrc = ((lane & 7) == 7) ? fmax(cv0, cv1) : -1.0e301;
#pragma unroll
        for (int off = 1; off < 64; off <<= 1) {
          double o = __shfl_xor(bsrc, off);
          bsrc = (o > bsrc) ? o : bsrc;
        }
        const double Bmax = bsrc;

        int cap = N_ANCH - nsel; if (cap > SCAP) cap = SCAP;
        int S = 0;
#pragma unroll 1
        while (S < cap) {
          bool p0 = (cv0 > cv1) || (cv0 == cv1 && ci0 < ci1);
          double wv = p0 ? cv0 : cv1;
          int   wix = p0 ? ci0 : ci1;
#pragma unroll
          for (int off = 1; off < 64; off <<= 1) {
            double ov = __shfl_xor(wv, off);
            int    oi = __shfl_xor(wix, off);
            bool bt = (ov > wv) || (ov == wv && oi < wix);
            wv = bt ? ov : wv; wix = bt ? oi : wix;
          }
          if (S != 0 && !(wv > Bmax)) break;   // unpublished point could beat it
          bool m0 = (ci0 == wix), m1 = (ci1 == wix);
          float fx = m0 ? cfx0 : cfx1;
          float fy = m0 ? cfy0 : cfy1;
          float fz = m0 ? cfz0 : cfz1;
          ull bal = __ballot(m0 || m1);
          int wl = __ffsll((long long)bal) - 1;
          fx = __shfl(fx, wl); fy = __shfl(fy, wl); fz = __shfl(fz, wl);
          double wx = (double)fx, wy = (double)fy, wz = (double)fz;
          if (lane == 0) {
            sm.f.bw[S][0] = wx; sm.f.bw[S][1] = wy; sm.f.bw[S][2] = wz;
            if (b == 0) ST_REL(anchors + nsel + S, wix);
          }
          cv0 = fmin(cv0, dist64((double)cfx0, (double)cfy0, (double)cfz0, wx, wy, wz));
          cv1 = fmin(cv1, dist64((double)cfx1, (double)cfy1, (double)cfz1, wx, wy, wz));
          if (m0) cv0 = -1.0e301;
          if (m1) cv1 = -1.0e301;
          S++;
        }
        if (lane == 0) sm.f.S = S;
      }
      __syncthreads();

      // ---- apply winners to md (min-chain is exactly order-independent) ----
      const int S = sm.f.S;
      bv = -1.0e301; bi = 0x7fffffff;
#pragma unroll
      for (int k = 0; k < PPT; ++k) {
        double dx0 = (double)px[k], dy0 = (double)py[k], dz0 = (double)pz[k];
        double m = md[k];
#pragma unroll 1
        for (int s = 0; s < S; ++s)
          m = fmin(m, dist64(dx0, dy0, dz0, sm.f.bw[s][0], sm.f.bw[s][1], sm.f.bw[s][2]));
        md[k] = m;
        int i = gtid + k * STRIDE;
        bool bt = (m > bv) || (m == bv && i < bi);
        bv = bt ? m : bv; bi = bt ? i : bi;
      }
      nsel += S;
      __syncthreads();   // protect sm.f.bw before next batch's wave0 writes
    }
  } else {
    // ========================= KNN (anchor-polling) =======================
    const int aidx = blockIdx.x - NB;
    if (t == 0) {
      int a;
      while ((a = LD_ACQ(anchors + aidx)) < 0) __builtin_amdgcn_s_sleep(16);
      sm.k.ai = a;
    }
    __syncthreads();
    const int ai = sm.k.ai;
    const float ax = pos[3 * ai], ay = pos[3 * ai + 1], az = pos[3 * ai + 2];

    ull key[KNN];
#pragma unroll
    for (int s = 0; s < KNN; ++s) key[s] = ~0ull;
    ull kmax = ~0ull; int smax = 0;
#pragma unroll 1
    for (int k = 0; k < (N_PTS + BT - 1) / BT; ++k) {
      int j = k * BT + t;
      if (j < N_PTS) {
        float dx = pos[3 * j] - ax, dy = pos[3 * j + 1] - ay, dz = pos[3 * j + 2] - az;
        float d  = dx * dx + dy * dy + dz * dz;
        ull nk = ((ull)__float_as_uint(d) << 32) | (unsigned)j;
        if (nk < kmax) {
#pragma unroll
          for (int s = 0; s < KNN; ++s) key[s] = (s == smax) ? nk : key[s];
          kmax = 0ull; smax = 0;
#pragma unroll
          for (int s = 0; s < KNN; ++s) {
            bool g = key[s] > kmax;
            kmax = g ? key[s] : kmax;
            smax = g ? s : smax;
          }
        }
      }
    }

    ull lmin = ~0ull; int ls = 0;
#pragma unroll
    for (int s = 0; s < KNN; ++s) {
      if (key[s] < lmin) { lmin = key[s]; ls = s; }
    }
#pragma unroll 1
    for (int r = 0; r < KNN; ++r) {
      ull mv = lmin;
#pragma unroll
      for (int off = 32; off >= 1; off >>= 1) {
        ull ov = __shfl_down(mv, off);
        mv = (ov < mv) ? ov : mv;
      }
      if (lane == 0) sm.k.m4[wave] = mv;
      __syncthreads();
      if (t == 0) {
        ull g = sm.k.m4[0];
#pragma unroll
        for (int w = 1; w < 4; ++w) g = (sm.k.m4[w] < g) ? sm.k.m4[w] : g;
        sm.k.g = g;
        sm.k.w[r] = (int)(g & 0xffffffffull);
      }
      __syncthreads();
      ull g = sm.k.g;
      if (lmin == g) {          // unique owner consumes & rescans
        key[ls] = ~0ull;
        lmin = ~0ull; ls = 0;
#pragma unroll
        for (int s = 0; s < KNN; ++s) {
          if (key[s] < lmin) { lmin = key[s]; ls = s; }
        }
      }
    }

    if (t == 0) {
      double mx = 0, my = 0, mz = 0;
      for (int r = 0; r < KNN; ++r) {
        int p = sm.k.w[r];
        mx += (double)pos[3 * p]; my += (double)pos[3 * p + 1]; mz += (double)pos[3 * p + 2];
      }
      mx /= KNN; my /= KNN; mz /= KNN;
      double xx = 0, xy = 0, xz = 0, yy = 0, yz = 0, zz = 0;
      for (int r = 0; r < KNN; ++r) {
        int p = sm.k.w[r];
        double cx = (double)pos[3 * p]     - mx;
        double cy = (double)pos[3 * p + 1] - my;
        double cz = (double)pos[3 * p + 2] - mz;
        xx += cx * cx; xy += cx * cy; xz += cx * cz;
        yy += cy * cy; yz += cy * cz; zz += cz * cz;
      }
      double v0, v1, v2;
      eig3_maxvec(xx, xy, xz, yy, yz, zz, v0, v1, v2);

      double a0 = vec_pred[3 * aidx], a1 = vec_pred[3 * aidx + 1], a2 = vec_pred[3 * aidx + 2];
      double an = sqrt(a0 * a0 + a1 * a1 + a2 * a2);
      double bn = sqrt(v0 * v0 + v1 * v1 + v2 * v2);
      double denom = fmax(an, 1e-8) * fmax(bn, 1e-8);
      double c = fabs((a0 * v0 + a1 * v1 + a2 * v2) / denom);
      atomicAdd(acc, log(c + 1e-6));
    }
  }
}

__global__ void finalize_kernel(const double* __restrict__ acc, float* __restrict__ out) {
  out[0] = (float)(-acc[0] / (double)N_ANCH);
}

// ===========================================================================
extern "C" void kernel_launch(void* const* d_in, const int* in_sizes, int n_in,
                              void* d_out, int out_size, void* d_ws, size_t ws_size,
                              hipStream_t stream) {
  (void)in_sizes; (void)n_in; (void)out_size; (void)ws_size;
  const float* vec_pred = (const float*)d_in[0];
  const float* pos      = (const float*)d_in[1];
  float* out = (float*)d_out;

  char* ws = (char*)d_ws;
  double* acc     = (double*)(ws + 0);
  ull*    keys    = (ull*)(ws + 256);
  ull*    exact   = (ull*)(ws + 4096);
  int*    anchors = (int*)(ws + 8192);

  hipMemsetAsync(ws, 0, 4096, stream);                  // acc + keys (tag=0)
  hipMemsetAsync(ws + 8192, 0xFF, N_ANCH * 4, stream);  // anchors = -1
  hipLaunchKernelGGL(fps_knn_kernel, dim3(NB + N_ANCH), dim3(BT), 0, stream,
                     pos, vec_pred, keys, exact, anchors, acc);
  hipLaunchKernelGGL(finalize_kernel, dim3(1), dim3(1), 0, stream, acc, out);
}

// Round 5
// 4828.997 us; speedup vs baseline: 7.4806x; 2.1327x over previous
//
#include <hip/hip_runtime.h>
#include <math.h>

#define N_PTS       40000
#define N_ANCH      4000     // ceil(0.1 * 40000)
#define KNN         20
#define NB          32       // fps blocks
#define BT          256      // threads per block (all blocks)
#define STRIDE      (NB * BT)          // 8192
#define PPT         5                  // 8192*5 = 40960 >= 40000
#define TOPT        8                  // published candidates per block
#define POOL        (NB * TOPT)       // 256
#define SCAP        128                // max anchors per batch

typedef unsigned long long ull;

#define LD_ACQ(p)    __hip_atomic_load((p),  __ATOMIC_ACQUIRE, __HIP_MEMORY_SCOPE_AGENT)
#define LD_RLX(p)    __hip_atomic_load((p),  __ATOMIC_RELAXED, __HIP_MEMORY_SCOPE_AGENT)
#define ST_REL(p,v)  __hip_atomic_store((p), (v), __ATOMIC_RELEASE, __HIP_MEMORY_SCOPE_AGENT)
#define ST_RLX(p,v)  __hip_atomic_store((p), (v), __ATOMIC_RELAXED, __HIP_MEMORY_SCOPE_AGENT)

// Workspace layout:
//   off    0 : double acc              (zeroed)
//   off  256 : ull keys[2][256]        (zeroed; tagged: idx<<2 | batch&3)
//   off 4352 : ull exact[2][256]       (f64 dist bits; ordered by key release)
//   off 8448 : int anchors[4000]       (memset 0xFF -> -1)

__device__ __forceinline__ double dist64(double px, double py, double pz,
                                         double wx, double wy, double wz) {
  double dx = px - wx, dy = py - wy, dz = pz - wz;
  return dx * dx + dy * dy + dz * dz;
}

struct FpsSm { double wtV[4][TOPT]; int wtI[4][TOPT]; };
struct KnnSm { ull m4[4]; ull g; int w[KNN]; int ai; };
union Smem { FpsSm f; KnnSm k; };

// ============== symmetric 3x3: eigenvector of largest eigenvalue ===========
__device__ static inline void eig3_maxvec(double xx, double xy, double xz,
                                          double yy, double yz, double zz,
                                          double& v0, double& v1, double& v2) {
  double q  = (xx + yy + zz) / 3.0;
  double p1 = xy * xy + xz * xz + yz * yz;
  double a00 = xx - q, a11 = yy - q, a22 = zz - q;
  double p2 = a00 * a00 + a11 * a11 + a22 * a22 + 2.0 * p1;
  if (p2 < 1e-300) { v0 = 1.0; v1 = 0.0; v2 = 0.0; return; }
  double p   = sqrt(p2 / 6.0);
  double inv = 1.0 / p;
  double b00 = a00 * inv, b01 = xy * inv, b02 = xz * inv;
  double b11 = a11 * inv, b12 = yz * inv, b22 = a22 * inv;
  double detB = b00 * (b11 * b22 - b12 * b12)
              - b01 * (b01 * b22 - b12 * b02)
              + b02 * (b01 * b12 - b11 * b02);
  double r = fmin(1.0, fmax(-1.0, detB * 0.5));
  double phi = acos(r) / 3.0;
  double lam = q + 2.0 * p * cos(phi);   // largest eigenvalue

  double r0x = xx - lam, r0y = xy,       r0z = xz;
  double r1x = xy,       r1y = yy - lam, r1z = yz;
  double r2x = xz,       r2y = yz,       r2z = zz - lam;
  double c0x = r0y * r1z - r0z * r1y, c0y = r0z * r1x - r0x * r1z, c0z = r0x * r1y - r0y * r1x;
  double c1x = r0y * r2z - r0z * r2y, c1y = r0z * r2x - r0x * r2z, c1z = r0x * r2y - r0y * r2x;
  double c2x = r1y * r2z - r1z * r2y, c2y = r1z * r2x - r1x * r2z, c2z = r1x * r2y - r1y * r2x;
  double n0 = c0x * c0x + c0y * c0y + c0z * c0z;
  double n1 = c1x * c1x + c1y * c1y + c1z * c1z;
  double n2 = c2x * c2x + c2y * c2y + c2z * c2z;
  double bx = c0x, by = c0y, bz = c0z, bn = n0;
  if (n1 > bn) { bx = c1x; by = c1y; bz = c1z; bn = n1; }
  if (n2 > bn) { bx = c2x; by = c2y; bz = c2z; bn = n2; }
  if (bn < 1e-280) { v0 = 1.0; v1 = 0.0; v2 = 0.0; return; }
  double s = 1.0 / sqrt(bn);
  v0 = bx * s; v1 = by * s; v2 = bz * s;
}

// ===========================================================================
__global__ __launch_bounds__(BT, 2) void fps_knn_kernel(
    const float* __restrict__ pos, const float* __restrict__ vec_pred,
    ull* __restrict__ keys, ull* __restrict__ exact,
    int* __restrict__ anchors, double* __restrict__ acc) {
  __shared__ Smem sm;
  const int t    = threadIdx.x;
  const int lane = t & 63;
  const int wave = t >> 6;

  if (blockIdx.x < NB) {
    // =========================== FPS (batched) ============================
    const int b    = blockIdx.x;
    const int gtid = b * BT + t;

    float px[PPT], py[PPT], pz[PPT];   // f32 coords (cvt to f64 is lossless)
    double md[PPT];
    const double a0x = (double)pos[0], a0y = (double)pos[1], a0z = (double)pos[2];
#pragma unroll
    for (int k = 0; k < PPT; ++k) {
      int i = gtid + k * STRIDE;
      if (i < N_PTS) {
        px[k] = pos[3 * i]; py[k] = pos[3 * i + 1]; pz[k] = pos[3 * i + 2];
        md[k] = dist64((double)px[k], (double)py[k], (double)pz[k], a0x, a0y, a0z);
      } else {
        px[k] = 0.f; py[k] = 0.f; pz[k] = 0.f;
        md[k] = -1.0e300;   // pad: never wins (every thread has >=4 real slots)
      }
    }
    if (b == 0 && t == 0) ST_REL(anchors + 0, 0);

    // maintained thread-local argmax (ties -> lowest global index)
    double bv = -1.0e301; int bi = 0x7fffffff;
#pragma unroll
    for (int k = 0; k < PPT; ++k) {
      int i = gtid + k * STRIDE;
      bool bt = (md[k] > bv) || (md[k] == bv && i < bi);
      bv = bt ? md[k] : bv; bi = bt ? i : bi;
    }

    int nsel  = 1;
    int batch = 0;
#pragma unroll 1
    while (nsel < N_ANCH) {
      batch++;
      const int par = batch & 1;
      const ull tag = (ull)(batch & 3);

      // ---- per-wave top-8 (shuffle-only butterflies) ----
      unsigned mask = 0;
#pragma unroll 1
      for (int r = 0; r < TOPT; ++r) {
        double rv = bv; int ri = bi;
#pragma unroll
        for (int off = 1; off < 64; off <<= 1) {
          double ov = __shfl_xor(rv, off);
          int    oi = __shfl_xor(ri, off);
          bool bt = (ov > rv) || (ov == rv && oi < ri);
          rv = bt ? ov : rv; ri = bt ? oi : ri;
        }
        if (ri == bi && bi != 0x7fffffff) {   // unique owner: mask & rescan
          mask |= 1u << ((unsigned)(ri - gtid) >> 13);   // STRIDE = 8192 = 2^13
          bv = -1.0e301; bi = 0x7fffffff;
#pragma unroll
          for (int k = 0; k < PPT; ++k) {
            if (!((mask >> k) & 1u)) {
              int i = gtid + k * STRIDE;
              bool bt = (md[k] > bv) || (md[k] == bv && i < bi);
              bv = bt ? md[k] : bv; bi = bt ? i : bi;
            }
          }
        }
        if (lane == r) { sm.f.wtV[wave][r] = rv; sm.f.wtI[wave][r] = ri; }
      }
      __syncthreads();   // the ONLY block barrier per batch

      // ---- wave0: merge 4x8 -> block top-8, publish to global pool ----
      if (wave == 0) {
        double mv = (lane < 32) ? sm.f.wtV[lane >> 3][lane & 7] : -1.0e301;
        int    mi = (lane < 32) ? sm.f.wtI[lane >> 3][lane & 7] : 0x7fffffff;
        double pv = -1.0e301; int pix = 0;
#pragma unroll 1
        for (int r = 0; r < TOPT; ++r) {
          double rv = mv; int ri = mi;
#pragma unroll
          for (int off = 1; off < 64; off <<= 1) {
            double ov = __shfl_xor(rv, off);
            int    oi = __shfl_xor(ri, off);
            bool bt = (ov > rv) || (ov == rv && oi < ri);
            rv = bt ? ov : rv; ri = bt ? oi : ri;
          }
          if (mi == ri) mv = -1.0e301;         // consume (owner unique)
          if (lane == r) { pv = rv; pix = ri; }
        }
        if (lane < TOPT) {
          ST_RLX(exact + par * POOL + b * TOPT + lane, (ull)__double_as_longlong(pv));
          // release store orders the exact store (same lane) before the key
          ST_REL(keys + par * POOL + b * TOPT + lane, ((ull)(unsigned)pix << 2) | tag);
        }
      }

      // ---- ALL waves: poll pool (4 slots/lane), replicated select+apply ----
      ull k0, k1, k2, k3;
      {
        ull* kb = keys + par * POOL;
        k0 = LD_ACQ(kb + lane);
        while ((k0 & 3ull) != tag) { __builtin_amdgcn_s_sleep(1); k0 = LD_ACQ(kb + lane); }
        k1 = LD_ACQ(kb + lane + 64);
        while ((k1 & 3ull) != tag) { __builtin_amdgcn_s_sleep(1); k1 = LD_ACQ(kb + lane + 64); }
        k2 = LD_ACQ(kb + lane + 128);
        while ((k2 & 3ull) != tag) { __builtin_amdgcn_s_sleep(1); k2 = LD_ACQ(kb + lane + 128); }
        k3 = LD_ACQ(kb + lane + 192);
        while ((k3 & 3ull) != tag) { __builtin_amdgcn_s_sleep(1); k3 = LD_ACQ(kb + lane + 192); }
      }
      double cv0 = __longlong_as_double((long long)LD_RLX(exact + par * POOL + lane));
      double cv1 = __longlong_as_double((long long)LD_RLX(exact + par * POOL + lane + 64));
      double cv2 = __longlong_as_double((long long)LD_RLX(exact + par * POOL + lane + 128));
      double cv3 = __longlong_as_double((long long)LD_RLX(exact + par * POOL + lane + 192));
      int ci0 = (int)(k0 >> 2), ci1 = (int)(k1 >> 2);
      int ci2 = (int)(k2 >> 2), ci3 = (int)(k3 >> 2);
      float cfx0 = pos[3 * ci0], cfy0 = pos[3 * ci0 + 1], cfz0 = pos[3 * ci0 + 2];
      float cfx1 = pos[3 * ci1], cfy1 = pos[3 * ci1 + 1], cfz1 = pos[3 * ci1 + 2];
      float cfx2 = pos[3 * ci2], cfy2 = pos[3 * ci2 + 1], cfz2 = pos[3 * ci2 + 2];
      float cfx3 = pos[3 * ci3], cfy3 = pos[3 * ci3 + 1], cfz3 = pos[3 * ci3 + 2];

      // Bmax = max over 32 blocks of their 8th (smallest published) value
      double bsrc = ((lane & 7) == 7)
          ? fmax(fmax(cv0, cv1), fmax(cv2, cv3)) : -1.0e301;
#pragma unroll
      for (int off = 1; off < 64; off <<= 1) {
        double o = __shfl_xor(bsrc, off);
        bsrc = (o > bsrc) ? o : bsrc;
      }
      const double Bmax = bsrc;

      int cap = N_ANCH - nsel; if (cap > SCAP) cap = SCAP;
      int S = 0;
#pragma unroll 1
      while (S < cap) {
        // local best of 4 (value desc, idx asc)
        double wv = cv0; int wix = ci0;
        { bool bt = (cv1 > wv) || (cv1 == wv && ci1 < wix); wv = bt ? cv1 : wv; wix = bt ? ci1 : wix; }
        { bool bt = (cv2 > wv) || (cv2 == wv && ci2 < wix); wv = bt ? cv2 : wv; wix = bt ? ci2 : wix; }
        { bool bt = (cv3 > wv) || (cv3 == wv && ci3 < wix); wv = bt ? cv3 : wv; wix = bt ? ci3 : wix; }
#pragma unroll
        for (int off = 1; off < 64; off <<= 1) {
          double ov = __shfl_xor(wv, off);
          int    oi = __shfl_xor(wix, off);
          bool bt = (ov > wv) || (ov == wv && oi < wix);
          wv = bt ? ov : wv; wix = bt ? oi : wix;
        }
        if (S != 0 && !(wv > Bmax)) break;   // unpublished point could beat it
        bool m0 = (ci0 == wix), m1 = (ci1 == wix), m2 = (ci2 == wix), m3 = (ci3 == wix);
        float fx = m0 ? cfx0 : m1 ? cfx1 : m2 ? cfx2 : cfx3;
        float fy = m0 ? cfy0 : m1 ? cfy1 : m2 ? cfy2 : cfy3;
        float fz = m0 ? cfz0 : m1 ? cfz1 : m2 ? cfz2 : cfz3;
        ull bal = __ballot(m0 || m1 || m2 || m3);
        int wl = __ffsll(bal) - 1;
        fx = __shfl(fx, wl); fy = __shfl(fy, wl); fz = __shfl(fz, wl);
        double wx = (double)fx, wy = (double)fy, wz = (double)fz;
        if (b == 0 && wave == 0 && lane == 0) ST_REL(anchors + nsel + S, wix);

        // update pool candidates
        cv0 = fmin(cv0, dist64((double)cfx0, (double)cfy0, (double)cfz0, wx, wy, wz));
        cv1 = fmin(cv1, dist64((double)cfx1, (double)cfy1, (double)cfz1, wx, wy, wz));
        cv2 = fmin(cv2, dist64((double)cfx2, (double)cfy2, (double)cfz2, wx, wy, wz));
        cv3 = fmin(cv3, dist64((double)cfx3, (double)cfy3, (double)cfz3, wx, wy, wz));
        if (m0) cv0 = -1.0e301;
        if (m1) cv1 = -1.0e301;
        if (m2) cv2 = -1.0e301;
        if (m3) cv3 = -1.0e301;

        // apply winner to own md slice (min-chain, exact f64)
#pragma unroll
        for (int k = 0; k < PPT; ++k)
          md[k] = fmin(md[k], dist64((double)px[k], (double)py[k], (double)pz[k], wx, wy, wz));
        S++;
      }
      nsel += S;

      // refresh thread-local argmax
      bv = -1.0e301; bi = 0x7fffffff;
#pragma unroll
      for (int k = 0; k < PPT; ++k) {
        int i = gtid + k * STRIDE;
        bool bt = (md[k] > bv) || (md[k] == bv && i < bi);
        bv = bt ? md[k] : bv; bi = bt ? i : bi;
      }
    }
  } else {
    // ========================= KNN (anchor-polling) =======================
    const int aidx = blockIdx.x - NB;
    if (t == 0) {
      int a = LD_ACQ(anchors + aidx);
      int spin = 1;
      while (a < 0) {
        for (int u = 0; u < spin; ++u) __builtin_amdgcn_s_sleep(32);
        if (spin < 32) spin <<= 1;
        a = LD_ACQ(anchors + aidx);
      }
      sm.k.ai = a;
    }
    __syncthreads();
    const int ai = sm.k.ai;
    const float ax = pos[3 * ai], ay = pos[3 * ai + 1], az = pos[3 * ai + 2];

    // per-thread top-20 (u64 keys, static indexing ONLY -> stays in VGPRs)
    ull key[KNN];
#pragma unroll
    for (int s = 0; s < KNN; ++s) key[s] = ~0ull;
    ull kmax = ~0ull; int smax = 0;
#pragma unroll 1
    for (int k = 0; k < (N_PTS + BT - 1) / BT; ++k) {
      int j = k * BT + t;
      if (j < N_PTS) {
        float dx = pos[3 * j] - ax, dy = pos[3 * j + 1] - ay, dz = pos[3 * j + 2] - az;
        float d  = dx * dx + dy * dy + dz * dz;
        ull nk = ((ull)__float_as_uint(d) << 32) | (unsigned)j;
        if (nk < kmax) {
#pragma unroll
          for (int s = 0; s < KNN; ++s) key[s] = (s == smax) ? nk : key[s];
          kmax = 0ull; smax = 0;
#pragma unroll
          for (int s = 0; s < KNN; ++s) {
            bool g = key[s] > kmax;
            kmax = g ? key[s] : kmax;
            smax = g ? s : smax;
          }
        }
      }
    }

    // block-wide merge: 20 extract-min rounds (consume via static unrolled select)
    ull lmin = ~0ull; int ls = 0;
#pragma unroll
    for (int s = 0; s < KNN; ++s) {
      bool l = key[s] < lmin;
      lmin = l ? key[s] : lmin; ls = l ? s : ls;
    }
#pragma unroll 1
    for (int r = 0; r < KNN; ++r) {
      ull mv = lmin;
#pragma unroll
      for (int off = 32; off >= 1; off >>= 1) {
        ull ov = __shfl_down(mv, off);
        mv = (ov < mv) ? ov : mv;
      }
      if (lane == 0) sm.k.m4[wave] = mv;
      __syncthreads();
      if (t == 0) {
        ull g = sm.k.m4[0];
#pragma unroll
        for (int w = 1; w < 4; ++w) g = (sm.k.m4[w] < g) ? sm.k.m4[w] : g;
        sm.k.g = g;
        sm.k.w[r] = (int)(g & 0xffffffffull);
      }
      __syncthreads();
      ull g = sm.k.g;
      if (lmin == g) {          // unique owner consumes & rescans (all static)
#pragma unroll
        for (int s = 0; s < KNN; ++s) key[s] = (s == ls) ? ~0ull : key[s];
        lmin = ~0ull; ls = 0;
#pragma unroll
        for (int s = 0; s < KNN; ++s) {
          bool l = key[s] < lmin;
          lmin = l ? key[s] : lmin; ls = l ? s : ls;
        }
      }
    }

    if (t == 0) {
      double mx = 0, my = 0, mz = 0;
      for (int r = 0; r < KNN; ++r) {
        int p = sm.k.w[r];
        mx += (double)pos[3 * p]; my += (double)pos[3 * p + 1]; mz += (double)pos[3 * p + 2];
      }
      mx /= KNN; my /= KNN; mz /= KNN;
      double xx = 0, xy = 0, xz = 0, yy = 0, yz = 0, zz = 0;
      for (int r = 0; r < KNN; ++r) {
        int p = sm.k.w[r];
        double cx = (double)pos[3 * p]     - mx;
        double cy = (double)pos[3 * p + 1] - my;
        double cz = (double)pos[3 * p + 2] - mz;
        xx += cx * cx; xy += cx * cy; xz += cx * cz;
        yy += cy * cy; yz += cy * cz; zz += cz * cz;
      }
      double v0, v1, v2;
      eig3_maxvec(xx, xy, xz, yy, yz, zz, v0, v1, v2);

      double a0 = vec_pred[3 * aidx], a1 = vec_pred[3 * aidx + 1], a2 = vec_pred[3 * aidx + 2];
      double an = sqrt(a0 * a0 + a1 * a1 + a2 * a2);
      double bn = sqrt(v0 * v0 + v1 * v1 + v2 * v2);
      double denom = fmax(an, 1e-8) * fmax(bn, 1e-8);
      double c = fabs((a0 * v0 + a1 * v1 + a2 * v2) / denom);
      atomicAdd(acc, log(c + 1e-6));
    }
  }
}

__global__ void finalize_kernel(const double* __restrict__ acc, float* __restrict__ out) {
  out[0] = (float)(-acc[0] / (double)N_ANCH);
}

// ===========================================================================
extern "C" void kernel_launch(void* const* d_in, const int* in_sizes, int n_in,
                              void* d_out, int out_size, void* d_ws, size_t ws_size,
                              hipStream_t stream) {
  (void)in_sizes; (void)n_in; (void)out_size; (void)ws_size;
  const float* vec_pred = (const float*)d_in[0];
  const float* pos      = (const float*)d_in[1];
  float* out = (float*)d_out;

  char* ws = (char*)d_ws;
  double* acc     = (double*)(ws + 0);
  ull*    keys    = (ull*)(ws + 256);
  ull*    exact   = (ull*)(ws + 4352);
  int*    anchors = (int*)(ws + 8448);

  hipMemsetAsync(ws, 0, 4352, stream);                  // acc + keys (tag=0)
  hipMemsetAsync(ws + 8448, 0xFF, N_ANCH * 4, stream);  // anchors = -1
  hipLaunchKernelGGL(fps_knn_kernel, dim3(NB + N_ANCH), dim3(BT), 0, stream,
                     pos, vec_pred, keys, exact, anchors, acc);
  hipLaunchKernelGGL(finalize_kernel, dim3(1), dim3(1), 0, stream, acc, out);
}